// Round 1
// baseline (192.304 us; speedup 1.0000x reference)
//
#include <hip/hip_runtime.h>
#include <stdint.h>

typedef __bf16 bf16;
typedef __bf16 bf16x8 __attribute__((ext_vector_type(8)));
typedef __bf16 bf16x4v __attribute__((ext_vector_type(4)));
typedef float f32x4 __attribute__((ext_vector_type(4)));

constexpr int B_N = 4, C_N = 512, T_N = 2048, H_N = 8, D_N = 64;
// M = B*T = 8192 rows for the QKV GEMM

__device__ __forceinline__ f32x4 mfma16(bf16x8 a, bf16x8 b, f32x4 c) {
  return __builtin_amdgcn_mfma_f32_16x16x32_bf16(a, b, c, 0, 0, 0);
}

// global -> LDS direct, 16B per lane. LDS dest is wave-uniform base + lane*16;
// global source is per-lane (lets us pre-swizzle the source for the T2 XOR swizzle).
#define GLOAD16(gp, lp)                                                        \
  __builtin_amdgcn_global_load_lds(                                            \
      (__attribute__((address_space(1))) void*)(uintptr_t)(const void*)(gp),   \
      (__attribute__((address_space(3))) void*)(uintptr_t)(void*)(lp), 16, 0, 0)

// ---------------------------------------------------------------- cvt weights
__global__ __launch_bounds__(256) void cvt_w(
    const float* __restrict__ w0, const float* __restrict__ w1,
    const float* __restrict__ w2, const float* __restrict__ w3,
    bf16* __restrict__ o0, bf16* __restrict__ o1,
    bf16* __restrict__ o2, bf16* __restrict__ o3) {
  int which = blockIdx.y;
  const float* s = which == 0 ? w0 : which == 1 ? w1 : which == 2 ? w2 : w3;
  bf16* d = which == 0 ? o0 : which == 1 ? o1 : which == 2 ? o2 : o3;
  int i = blockIdx.x * 256 + threadIdx.x;  // 65536 threads, 4 elems each
  float4 v = ((const float4*)s)[i];
  bf16x4v pk = {(bf16)v.x, (bf16)v.y, (bf16)v.z, (bf16)v.w};
  *(bf16x4v*)(d + (size_t)i * 4) = pk;
}

// -------------------------------------------------- LayerNorm + transpose
// x [B,C,T] fp32 -> xn [B*T, C] bf16 (row t of batch b at (b*T+t)*C)
__global__ __launch_bounds__(256) void ln_tr(
    const float* __restrict__ x, const float* __restrict__ gamma,
    const float* __restrict__ beta, bf16* __restrict__ xn) {
  __shared__ bf16 tile[32 * 520];           // [32 t][512 c], stride 520 (16B-aligned rows)
  __shared__ float red[2][8][32];
  __shared__ float mu_s[32], rs_s[32];
  const int b = blockIdx.y;
  const int t0 = blockIdx.x * 32;
  const int tid = threadIdx.x;
  const int lt = tid & 31;                  // t within tile
  const int cr = tid >> 5;                  // 0..7
  const float* xp = x + ((size_t)b * C_N) * T_N + t0 + lt;
  float sum = 0.f, ss = 0.f;
  for (int c = cr; c < C_N; c += 8) {
    float v = xp[(size_t)c * T_N];
    tile[lt * 520 + c] = (bf16)v;
    sum += v;
    ss += v * v;
  }
  red[0][cr][lt] = sum;
  red[1][cr][lt] = ss;
  __syncthreads();
  if (tid < 32) {
    float s = 0.f, q = 0.f;
    for (int j = 0; j < 8; ++j) { s += red[0][j][tid]; q += red[1][j][tid]; }
    float mu = s * (1.f / 512.f);
    float var = q * (1.f / 512.f) - mu * mu;
    mu_s[tid] = mu;
    rs_s[tid] = rsqrtf(var + 1e-5f);
  }
  __syncthreads();
#pragma unroll
  for (int p = 0; p < 8; ++p) {
    int ch = p * 256 + tid;                 // 2048 chunks of 8 elems
    int t = ch >> 6;
    int c0 = (ch & 63) * 8;
    float mu = mu_s[t], rs = rs_s[t];
    bf16x8 in = *(const bf16x8*)(tile + t * 520 + c0);
    bf16x8 ov;
#pragma unroll
    for (int e = 0; e < 8; ++e) {
      float g = gamma[c0 + e], bb = beta[c0 + e];
      ov[e] = (bf16)(((float)in[e] - mu) * rs * g + bb);
    }
    *(bf16x8*)(xn + ((size_t)(b * T_N + t0 + t)) * C_N + c0) = ov;
  }
}

// ------------------------------------------------ shared 128x128x(K) GEMM core
// C[m][n] = sum_k A[m0+m][k] * B[n0+n][k]   (both operands row-major [rows][K])
// XOR-swizzled LDS (chunk ^= row&7) with pre-swizzled global source.
template <int KDIM>
__device__ __forceinline__ void gemm128_core(const bf16* __restrict__ Ag,
                                             const bf16* __restrict__ Bg,
                                             bf16* As, bf16* Bs,
                                             f32x4 acc[4][4]) {
  const int tid = threadIdx.x;
  const int lane = tid & 63;
  const int wave = tid >> 6;
  const int wm = wave >> 1, wn = wave & 1;
  const int l15 = lane & 15, l4 = lane >> 4;
  f32x4 zero = {0.f, 0.f, 0.f, 0.f};
#pragma unroll
  for (int i = 0; i < 4; ++i)
#pragma unroll
    for (int j = 0; j < 4; ++j) acc[i][j] = zero;

  for (int kt = 0; kt < KDIM / 64; ++kt) {
    const bf16* a0 = Ag + kt * 64;
    const bf16* b0 = Bg + kt * 64;
#pragma unroll
    for (int p = 0; p < 4; ++p) {
      int chunk = p * 256 + tid;            // 1024 chunks of 16B per tile
      int row = chunk >> 3, c = chunk & 7;
      int sc = c ^ (row & 7);
      GLOAD16(a0 + (size_t)row * KDIM + sc * 8, As + chunk * 8);
      GLOAD16(b0 + (size_t)row * KDIM + sc * 8, Bs + chunk * 8);
    }
    __syncthreads();
#pragma unroll
    for (int ks = 0; ks < 2; ++ks) {
      bf16x8 af[4], bfr[4];
#pragma unroll
      for (int i = 0; i < 4; ++i) {
        int row = wm * 64 + i * 16 + l15;
        int kc = ks * 4 + l4;
        af[i] = *(const bf16x8*)(As + row * 64 + ((kc ^ (row & 7)) << 3));
      }
#pragma unroll
      for (int j = 0; j < 4; ++j) {
        int row = wn * 64 + j * 16 + l15;
        int kc = ks * 4 + l4;
        bfr[j] = *(const bf16x8*)(Bs + row * 64 + ((kc ^ (row & 7)) << 3));
      }
#pragma unroll
      for (int i = 0; i < 4; ++i)
#pragma unroll
        for (int j = 0; j < 4; ++j) acc[i][j] = mfma16(af[i], bfr[j], acc[i][j]);
    }
    __syncthreads();
  }
}

// ---------------------------------------------------------------- QKV GEMM
// z=0: Q -> [B,H,T,D]; z=1: K -> [B,H,T,D]; z=2: V -> transposed [B,H,D,T]
__global__ __launch_bounds__(256) void gemm_qkv(
    const bf16* __restrict__ xn, const bf16* __restrict__ wq,
    const bf16* __restrict__ wk, const bf16* __restrict__ wv,
    const float* __restrict__ bq, const float* __restrict__ bk,
    const float* __restrict__ bv, bf16* __restrict__ q, bf16* __restrict__ k,
    bf16* __restrict__ vt) {
  __shared__ bf16 lds[128 * 136];           // 34.8KB: GEMM tiles + V transpose
  bf16* As = lds;
  bf16* Bs = lds + 128 * 64;
  const int z = blockIdx.z;
  const bf16* W = z == 0 ? wq : z == 1 ? wk : wv;
  const float* bias = z == 0 ? bq : z == 1 ? bk : bv;
  const int m0 = blockIdx.x * 128;
  const int n0 = blockIdx.y * 128;
  f32x4 acc[4][4];
  gemm128_core<512>(xn + (size_t)m0 * 512, W + (size_t)n0 * 512, As, Bs, acc);

  const int tid = threadIdx.x, lane = tid & 63, wave = tid >> 6;
  const int wm = wave >> 1, wn = wave & 1;
  const int l15 = lane & 15, l4 = lane >> 4;
  const int b = m0 >> 11;                   // m0 / T
  const int t0 = m0 & (T_N - 1);

  if (z < 2) {
    bf16* outp = z == 0 ? q : k;
#pragma unroll
    for (int i = 0; i < 4; ++i) {
      int t = t0 + wm * 64 + i * 16 + l4 * 4;
#pragma unroll
      for (int j = 0; j < 4; ++j) {
        int n = n0 + wn * 64 + j * 16 + l15;
        int h = n >> 6, d = n & 63;
        bf16* dst = outp + (((size_t)(b * H_N + h) * T_N) + t) * D_N + d;
        float bv_ = bias[n];
#pragma unroll
        for (int r = 0; r < 4; ++r) dst[(size_t)r * D_N] = (bf16)(acc[i][j][r] + bv_);
      }
    }
  } else {
    // transpose through LDS: lds2[n_local][m_local], stride 136
#pragma unroll
    for (int i = 0; i < 4; ++i) {
      int ml = wm * 64 + i * 16 + l4 * 4;
#pragma unroll
      for (int j = 0; j < 4; ++j) {
        int nl = wn * 64 + j * 16 + l15;
        float bv_ = bias[n0 + nl];
#pragma unroll
        for (int r = 0; r < 4; ++r) lds[nl * 136 + ml + r] = (bf16)(acc[i][j][r] + bv_);
      }
    }
    __syncthreads();
#pragma unroll
    for (int p = 0; p < 8; ++p) {
      int ch = p * 256 + tid;               // 2048 chunks of 8
      int row = ch >> 4;                    // n_local 0..127
      int cm = (ch & 15) * 8;               // m offset
      int n = n0 + row;
      int h = n >> 6, d = n & 63;
      bf16x8 v = *(const bf16x8*)(lds + row * 136 + cm);
      *(bf16x8*)(vt + (((size_t)(b * H_N + h) * D_N + d) * T_N) + t0 + cm) = v;
    }
  }
}

// ---------------------------------------------------------------- attention
// q,k: [B,H,T,D]; vt: [B,H,D,T]; out ao: [B,T,C] bf16. Q pre-scaled by 1/8.
__global__ __launch_bounds__(256) void attn(const bf16* __restrict__ q,
                                            const bf16* __restrict__ kk,
                                            const bf16* __restrict__ vt,
                                            bf16* __restrict__ ao) {
  __shared__ bf16 Ks[64 * 64];              // 8KB, swizzled
  __shared__ bf16 Vs[64 * 64];              // 8KB (V^T tile: [d][t]), swizzled
  __shared__ bf16 Ps[4][32 * 72];           // per-wave P, row stride 72 (144B, 16B-aligned)
  const int bh = blockIdx.y;
  const int q0 = blockIdx.x * 128;
  const int tid = threadIdx.x, lane = tid & 63, wave = tid >> 6;
  const int l15 = lane & 15, l4 = lane >> 4;
  const bf16* qp = q + (size_t)bh * T_N * D_N;
  const bf16* kp = kk + (size_t)bh * T_N * D_N;
  const bf16* vp = vt + (size_t)bh * D_N * T_N;
  const int qbase = q0 + wave * 32;

  // Q fragments in registers, pre-scaled by 0.125 (exact in bf16)
  bf16x8 qf[2][2];
#pragma unroll
  for (int mi = 0; mi < 2; ++mi)
#pragma unroll
    for (int ks = 0; ks < 2; ++ks) {
      bf16x8 v = *(const bf16x8*)(qp + (size_t)(qbase + mi * 16 + l15) * D_N + ks * 32 + l4 * 8);
#pragma unroll
      for (int e = 0; e < 8; ++e) v[e] = (bf16)((float)v[e] * 0.125f);
      qf[mi][ks] = v;
    }

  f32x4 zero = {0.f, 0.f, 0.f, 0.f};
  f32x4 o[2][4];
  float mrun[2][4], lrun[2][4];
#pragma unroll
  for (int mi = 0; mi < 2; ++mi) {
#pragma unroll
    for (int di = 0; di < 4; ++di) o[mi][di] = zero;
#pragma unroll
    for (int r = 0; r < 4; ++r) { mrun[mi][r] = -1e30f; lrun[mi][r] = 0.f; }
  }
  bf16* Pw = Ps[wave];

  for (int kv = 0; kv < T_N; kv += 64) {
    // stage K tile [64 kv][64 d] and V^T tile [64 d][64 t], both swizzled
#pragma unroll
    for (int p = 0; p < 2; ++p) {
      int chunk = p * 256 + tid;            // 512 chunks each
      int row = chunk >> 3, c = chunk & 7;
      int sc = c ^ (row & 7);
      GLOAD16(kp + (size_t)(kv + row) * D_N + sc * 8, Ks + chunk * 8);
      GLOAD16(vp + (size_t)row * T_N + kv + sc * 8, Vs + chunk * 8);
    }
    __syncthreads();

    // S = Q K^T  (rows q, cols kv)
    f32x4 s[2][4];
#pragma unroll
    for (int mi = 0; mi < 2; ++mi)
#pragma unroll
      for (int ni = 0; ni < 4; ++ni) s[mi][ni] = zero;
#pragma unroll
    for (int ks = 0; ks < 2; ++ks) {
      bf16x8 kb[4];
#pragma unroll
      for (int ni = 0; ni < 4; ++ni) {
        int row = ni * 16 + l15;
        int kc = ks * 4 + l4;
        kb[ni] = *(const bf16x8*)(Ks + row * 64 + ((kc ^ (row & 7)) << 3));
      }
#pragma unroll
      for (int mi = 0; mi < 2; ++mi)
#pragma unroll
        for (int ni = 0; ni < 4; ++ni) s[mi][ni] = mfma16(qf[mi][ks], kb[ni], s[mi][ni]);
    }

    // online softmax (wave-parallel: reduce over the 16 lanes sharing a row)
#pragma unroll
    for (int mi = 0; mi < 2; ++mi) {
#pragma unroll
      for (int r = 0; r < 4; ++r) {
        float v0 = fmaxf(fmaxf(s[mi][0][r], s[mi][1][r]),
                         fmaxf(s[mi][2][r], s[mi][3][r]));
#pragma unroll
        for (int off = 1; off < 16; off <<= 1) v0 = fmaxf(v0, __shfl_xor(v0, off));
        float mnew = fmaxf(mrun[mi][r], v0);
        float alpha = __expf(mrun[mi][r] - mnew);
        float rs = 0.f;
#pragma unroll
        for (int ni = 0; ni < 4; ++ni) {
          float pv = __expf(s[mi][ni][r] - mnew);
          s[mi][ni][r] = pv;
          rs += pv;
        }
#pragma unroll
        for (int off = 1; off < 16; off <<= 1) rs += __shfl_xor(rs, off);
        lrun[mi][r] = lrun[mi][r] * alpha + rs;
        mrun[mi][r] = mnew;
#pragma unroll
        for (int di = 0; di < 4; ++di) o[mi][di][r] *= alpha;
      }
      // write P (bf16) to this wave's LDS region
#pragma unroll
      for (int ni = 0; ni < 4; ++ni) {
        int col = ni * 16 + l15;
#pragma unroll
        for (int r = 0; r < 4; ++r) {
          int row = mi * 16 + l4 * 4 + r;
          Pw[row * 72 + col] = (bf16)s[mi][ni][r];
        }
      }
    }
    asm volatile("s_waitcnt lgkmcnt(0)" ::: "memory");
    __builtin_amdgcn_sched_barrier(0);

    // O += P V   (A = P rows q, B = V^T rows d)
#pragma unroll
    for (int ks = 0; ks < 2; ++ks) {
      bf16x8 pa[2], vb[4];
#pragma unroll
      for (int mi = 0; mi < 2; ++mi)
        pa[mi] = *(const bf16x8*)(Pw + (mi * 16 + l15) * 72 + ks * 32 + l4 * 8);
#pragma unroll
      for (int di = 0; di < 4; ++di) {
        int row = di * 16 + l15;
        int kc = ks * 4 + l4;
        vb[di] = *(const bf16x8*)(Vs + row * 64 + ((kc ^ (row & 7)) << 3));
      }
#pragma unroll
      for (int mi = 0; mi < 2; ++mi)
#pragma unroll
        for (int di = 0; di < 4; ++di) o[mi][di] = mfma16(pa[mi], vb[di], o[mi][di]);
    }
    __syncthreads();
  }

  // epilogue: normalize and write [B,T,C]
  const int b = bh >> 3, h = bh & 7;
#pragma unroll
  for (int mi = 0; mi < 2; ++mi) {
#pragma unroll
    for (int r = 0; r < 4; ++r) {
      int t = qbase + mi * 16 + l4 * 4 + r;
      float inv = 1.f / lrun[mi][r];
#pragma unroll
      for (int di = 0; di < 4; ++di) {
        int c = h * D_N + di * 16 + l15;
        ao[((size_t)(b * T_N + t)) * C_N + c] = (bf16)(o[mi][di][r] * inv);
      }
    }
  }
}

// -------------------------------------------------------------- out projection
// out[b][c][t] = sum_k Wo[c][k]*ao[b][t][k] + bo[c] + x[b][c][t]  (fp32 out)
__global__ __launch_bounds__(256) void gemm_out(
    const bf16* __restrict__ wo, const bf16* __restrict__ ao,
    const float* __restrict__ bo, const float* __restrict__ x,
    float* __restrict__ out) {
  __shared__ bf16 lds[2 * 128 * 64];
  const int m0 = blockIdx.x * 128;          // c rows
  const int n0 = blockIdx.y * 128;          // t cols
  const int b = blockIdx.z;
  f32x4 acc[4][4];
  gemm128_core<512>(wo + (size_t)m0 * 512,
                    ao + (size_t)b * T_N * C_N + (size_t)n0 * 512,
                    lds, lds + 128 * 64, acc);
  const int tid = threadIdx.x, lane = tid & 63, wave = tid >> 6;
  const int wm = wave >> 1, wn = wave & 1;
  const int l15 = lane & 15, l4 = lane >> 4;
#pragma unroll
  for (int i = 0; i < 4; ++i) {
#pragma unroll
    for (int r = 0; r < 4; ++r) {
      int cr_ = m0 + wm * 64 + i * 16 + l4 * 4 + r;
      float bias = bo[cr_];
      const float* xrow = x + ((size_t)b * C_N + cr_) * T_N;
      float* orow = out + ((size_t)b * C_N + cr_) * T_N;
#pragma unroll
      for (int j = 0; j < 4; ++j) {
        int tc = n0 + wn * 64 + j * 16 + l15;
        orow[tc] = acc[i][j][r] + bias + xrow[tc];
      }
    }
  }
}

// ------------------------------------------------------------------- launcher
extern "C" void kernel_launch(void* const* d_in, const int* in_sizes, int n_in,
                              void* d_out, int out_size, void* d_ws,
                              size_t ws_size, hipStream_t stream) {
  const float* x = (const float*)d_in[0];
  const float* Wq = (const float*)d_in[1];
  const float* bq = (const float*)d_in[2];
  const float* Wk = (const float*)d_in[3];
  const float* bk = (const float*)d_in[4];
  const float* Wv = (const float*)d_in[5];
  const float* bv = (const float*)d_in[6];
  const float* Wo = (const float*)d_in[7];
  const float* bo = (const float*)d_in[8];
  const float* gamma = (const float*)d_in[9];
  const float* beta = (const float*)d_in[10];
  float* out = (float*)d_out;

  bf16* wq_b = (bf16*)d_ws;                       // 4 x 262144 bf16
  bf16* wk_b = wq_b + 262144;
  bf16* wv_b = wk_b + 262144;
  bf16* wo_b = wv_b + 262144;
  bf16* xn = wo_b + 262144;                       // 8192*512
  bf16* qb = xn + (size_t)8192 * 512;             // [B,H,T,D]
  bf16* kb = qb + (size_t)4194304;                // [B,H,T,D]
  bf16* vtb = kb + (size_t)4194304;               // [B,H,D,T]
  bf16* aob = vtb + (size_t)4194304;              // [B,T,C]

  cvt_w<<<dim3(256, 4), 256, 0, stream>>>(Wq, Wk, Wv, Wo, wq_b, wk_b, wv_b, wo_b);
  ln_tr<<<dim3(T_N / 32, B_N), 256, 0, stream>>>(x, gamma, beta, xn);
  gemm_qkv<<<dim3(64, 4, 3), 256, 0, stream>>>(xn, wq_b, wk_b, wv_b, bq, bk, bv,
                                               qb, kb, vtb);
  attn<<<dim3(T_N / 128, B_N * H_N), 256, 0, stream>>>(qb, kb, vtb, aob);
  gemm_out<<<dim3(4, 16, 4), 256, 0, stream>>>(wo_b, aob, bo, x, out);
}

// Round 2
// 125.082 us; speedup vs baseline: 1.5374x; 1.5374x over previous
//
#include <hip/hip_runtime.h>
#include <stdint.h>

typedef __bf16 bf16;
typedef __bf16 bf16x8 __attribute__((ext_vector_type(8)));
typedef __bf16 bf16x4v __attribute__((ext_vector_type(4)));
typedef float f32x4 __attribute__((ext_vector_type(4)));

constexpr int B_N = 4, C_N = 512, T_N = 2048, H_N = 8, D_N = 64;

__device__ __forceinline__ f32x4 mfma16(bf16x8 a, bf16x8 b, f32x4 c) {
  return __builtin_amdgcn_mfma_f32_16x16x32_bf16(a, b, c, 0, 0, 0);
}

#define GLOAD16(gp, lp)                                                        \
  __builtin_amdgcn_global_load_lds(                                            \
      (__attribute__((address_space(1))) void*)(uintptr_t)(const void*)(gp),   \
      (__attribute__((address_space(3))) void*)(uintptr_t)(void*)(lp), 16, 0, 0)

// ---------------------------------------------------------------- cvt weights
__global__ __launch_bounds__(256) void cvt_w(
    const float* __restrict__ w0, const float* __restrict__ w1,
    const float* __restrict__ w2, const float* __restrict__ w3,
    bf16* __restrict__ o0, bf16* __restrict__ o1,
    bf16* __restrict__ o2, bf16* __restrict__ o3) {
  int which = blockIdx.y;
  const float* s = which == 0 ? w0 : which == 1 ? w1 : which == 2 ? w2 : w3;
  bf16* d = which == 0 ? o0 : which == 1 ? o1 : which == 2 ? o2 : o3;
  int i = blockIdx.x * 256 + threadIdx.x;
  float4 v = ((const float4*)s)[i];
  bf16x4v pk = {(bf16)v.x, (bf16)v.y, (bf16)v.z, (bf16)v.w};
  *(bf16x4v*)(d + (size_t)i * 4) = pk;
}

// -------------------------------------------------- LayerNorm + transpose
__global__ __launch_bounds__(256) void ln_tr(
    const float* __restrict__ x, const float* __restrict__ gamma,
    const float* __restrict__ beta, bf16* __restrict__ xn) {
  __shared__ bf16 tile[32 * 520];
  __shared__ float red[2][8][32];
  __shared__ float mu_s[32], rs_s[32];
  const int b = blockIdx.y;
  const int t0 = blockIdx.x * 32;
  const int tid = threadIdx.x;
  const int lt = tid & 31;
  const int cr = tid >> 5;
  const float* xp = x + ((size_t)b * C_N) * T_N + t0 + lt;
  float sum = 0.f, ss = 0.f;
  for (int c = cr; c < C_N; c += 8) {
    float v = xp[(size_t)c * T_N];
    tile[lt * 520 + c] = (bf16)v;
    sum += v;
    ss += v * v;
  }
  red[0][cr][lt] = sum;
  red[1][cr][lt] = ss;
  __syncthreads();
  if (tid < 32) {
    float s = 0.f, q = 0.f;
    for (int j = 0; j < 8; ++j) { s += red[0][j][tid]; q += red[1][j][tid]; }
    float mu = s * (1.f / 512.f);
    float var = q * (1.f / 512.f) - mu * mu;
    mu_s[tid] = mu;
    rs_s[tid] = rsqrtf(var + 1e-5f);
  }
  __syncthreads();
#pragma unroll
  for (int p = 0; p < 8; ++p) {
    int ch = p * 256 + tid;
    int t = ch >> 6;
    int c0 = (ch & 63) * 8;
    float mu = mu_s[t], rs = rs_s[t];
    bf16x8 in = *(const bf16x8*)(tile + t * 520 + c0);
    bf16x8 ov;
#pragma unroll
    for (int e = 0; e < 8; ++e) {
      float g = gamma[c0 + e], bb = beta[c0 + e];
      ov[e] = (bf16)(((float)in[e] - mu) * rs * g + bb);
    }
    *(bf16x8*)(xn + ((size_t)(b * T_N + t0 + t)) * C_N + c0) = ov;
  }
}

// ------------------------------------------------ shared 128x128x(K) GEMM core
template <int KDIM>
__device__ __forceinline__ void gemm128_core(const bf16* __restrict__ Ag,
                                             const bf16* __restrict__ Bg,
                                             bf16* As, bf16* Bs,
                                             f32x4 acc[4][4]) {
  const int tid = threadIdx.x;
  const int lane = tid & 63;
  const int wave = tid >> 6;
  const int wm = wave >> 1, wn = wave & 1;
  const int l15 = lane & 15, l4 = lane >> 4;
  f32x4 zero = {0.f, 0.f, 0.f, 0.f};
#pragma unroll
  for (int i = 0; i < 4; ++i)
#pragma unroll
    for (int j = 0; j < 4; ++j) acc[i][j] = zero;

  for (int kt = 0; kt < KDIM / 64; ++kt) {
    const bf16* a0 = Ag + kt * 64;
    const bf16* b0 = Bg + kt * 64;
#pragma unroll
    for (int p = 0; p < 4; ++p) {
      int chunk = p * 256 + tid;
      int row = chunk >> 3, c = chunk & 7;
      int sc = c ^ (row & 7);
      GLOAD16(a0 + (size_t)row * KDIM + sc * 8, As + chunk * 8);
      GLOAD16(b0 + (size_t)row * KDIM + sc * 8, Bs + chunk * 8);
    }
    __syncthreads();
#pragma unroll
    for (int ks = 0; ks < 2; ++ks) {
      bf16x8 af[4], bfr[4];
#pragma unroll
      for (int i = 0; i < 4; ++i) {
        int row = wm * 64 + i * 16 + l15;
        int kc = ks * 4 + l4;
        af[i] = *(const bf16x8*)(As + row * 64 + ((kc ^ (row & 7)) << 3));
      }
#pragma unroll
      for (int j = 0; j < 4; ++j) {
        int row = wn * 64 + j * 16 + l15;
        int kc = ks * 4 + l4;
        bfr[j] = *(const bf16x8*)(Bs + row * 64 + ((kc ^ (row & 7)) << 3));
      }
#pragma unroll
      for (int i = 0; i < 4; ++i)
#pragma unroll
        for (int j = 0; j < 4; ++j) acc[i][j] = mfma16(af[i], bfr[j], acc[i][j]);
    }
    __syncthreads();
  }
}

// ---------------------------------------------------------------- QKV GEMM
__global__ __launch_bounds__(256) void gemm_qkv(
    const bf16* __restrict__ xn, const bf16* __restrict__ wq,
    const bf16* __restrict__ wk, const bf16* __restrict__ wv,
    const float* __restrict__ bq, const float* __restrict__ bk,
    const float* __restrict__ bv, bf16* __restrict__ q, bf16* __restrict__ k,
    bf16* __restrict__ vt) {
  __shared__ bf16 lds[128 * 136];
  bf16* As = lds;
  bf16* Bs = lds + 128 * 64;
  const int z = blockIdx.z;
  const bf16* W = z == 0 ? wq : z == 1 ? wk : wv;
  const float* bias = z == 0 ? bq : z == 1 ? bk : bv;
  const int m0 = blockIdx.x * 128;
  const int n0 = blockIdx.y * 128;
  f32x4 acc[4][4];
  gemm128_core<512>(xn + (size_t)m0 * 512, W + (size_t)n0 * 512, As, Bs, acc);

  const int tid = threadIdx.x, lane = tid & 63, wave = tid >> 6;
  const int wm = wave >> 1, wn = wave & 1;
  const int l15 = lane & 15, l4 = lane >> 4;
  const int b = m0 >> 11;
  const int t0 = m0 & (T_N - 1);

  if (z < 2) {
    bf16* outp = z == 0 ? q : k;
#pragma unroll
    for (int i = 0; i < 4; ++i) {
      int t = t0 + wm * 64 + i * 16 + l4 * 4;
#pragma unroll
      for (int j = 0; j < 4; ++j) {
        int n = n0 + wn * 64 + j * 16 + l15;
        int h = n >> 6, d = n & 63;
        bf16* dst = outp + (((size_t)(b * H_N + h) * T_N) + t) * D_N + d;
        float bv_ = bias[n];
#pragma unroll
        for (int r = 0; r < 4; ++r) dst[(size_t)r * D_N] = (bf16)(acc[i][j][r] + bv_);
      }
    }
  } else {
#pragma unroll
    for (int i = 0; i < 4; ++i) {
      int ml = wm * 64 + i * 16 + l4 * 4;
#pragma unroll
      for (int j = 0; j < 4; ++j) {
        int nl = wn * 64 + j * 16 + l15;
        float bv_ = bias[n0 + nl];
#pragma unroll
        for (int r = 0; r < 4; ++r) lds[nl * 136 + ml + r] = (bf16)(acc[i][j][r] + bv_);
      }
    }
    __syncthreads();
#pragma unroll
    for (int p = 0; p < 8; ++p) {
      int ch = p * 256 + tid;
      int row = ch >> 4;
      int cm = (ch & 15) * 8;
      int n = n0 + row;
      int h = n >> 6, d = n & 63;
      bf16x8 v = *(const bf16x8*)(lds + row * 136 + cm);
      *(bf16x8*)(vt + (((size_t)(b * H_N + h) * D_N + d) * T_N) + t0 + cm) = v;
    }
  }
}

// ---------------------------------------------------------------- attention
// Swapped-operand flash attention: S^T = mfma(K,Q), O^T = mfma(V^T,P).
// K rows staged with a bit-permutation so each lane's S^T values are exactly
// the PV B-fragment slots -> P stays in registers (no LDS round-trip).
__global__ __launch_bounds__(256, 2) void attn(const bf16* __restrict__ q,
                                               const bf16* __restrict__ kk,
                                               const bf16* __restrict__ vt,
                                               bf16* __restrict__ ao) {
  __shared__ __align__(16) bf16 smem[16384];  // 2 bufs x (K 4096 + V 4096)
  const int bh = blockIdx.y;
  const int q0 = blockIdx.x * 128;
  const int tid = threadIdx.x, lane = tid & 63, wave = tid >> 6;
  const int l15 = lane & 15, l4 = lane >> 4;
  const bf16* qp = q + (size_t)bh * T_N * D_N;
  const bf16* kp = kk + (size_t)bh * T_N * D_N;
  const bf16* vp = vt + (size_t)bh * D_N * T_N;
  const int qw0 = q0 + wave * 32;

  // staging offsets: chunk -> (row, swizzled col); K source row bit-permuted:
  // rho = [b5 b4 b3 b2 b1 b0] -> kv = b5*32 + (b3b2)*8 + b4*4 + (b1b0)
  int kgoff[2], vgoff[2], ldsoff[2];
#pragma unroll
  for (int p = 0; p < 2; ++p) {
    int chunk = p * 256 + tid;
    int row = chunk >> 3, c = chunk & 7, sc = c ^ (row & 7);
    int kvp = (row & 0x23) | ((row & 0x0C) << 1) | ((row & 0x10) >> 2);
    kgoff[p] = kvp * 64 + sc * 8;
    vgoff[p] = row * T_N + sc * 8;
    ldsoff[p] = chunk * 8;
  }

  // Q fragments (B-operand), pre-scaled by 1/8 (exact in bf16)
  bf16x8 qf[2][2];
#pragma unroll
  for (int nq = 0; nq < 2; ++nq)
#pragma unroll
    for (int ks = 0; ks < 2; ++ks) {
      bf16x8 v = *(const bf16x8*)(qp + (size_t)(qw0 + nq * 16 + l15) * D_N +
                                  ks * 32 + l4 * 8);
#pragma unroll
      for (int e = 0; e < 8; ++e) v[e] = (bf16)((float)v[e] * 0.125f);
      qf[nq][ks] = v;
    }

  f32x4 zero = {0.f, 0.f, 0.f, 0.f};
  f32x4 o[2][4];                        // o[nq][di]: O^T[d=di*16+l4*4+r][q=l15]
  float m[2] = {-1e30f, -1e30f}, l[2] = {0.f, 0.f};
#pragma unroll
  for (int nq = 0; nq < 2; ++nq)
#pragma unroll
    for (int di = 0; di < 4; ++di) o[nq][di] = zero;

  // prologue stage
#pragma unroll
  for (int p = 0; p < 2; ++p) {
    GLOAD16(kp + kgoff[p], smem + ldsoff[p]);
    GLOAD16(vp + vgoff[p], smem + 4096 + ldsoff[p]);
  }
  __syncthreads();

  for (int t = 0; t < T_N / 64; ++t) {
    const int buf = t & 1;
    if (t + 1 < T_N / 64) {               // issue next tile early (T14)
      const bf16* kpt = kp + (t + 1) * 64 * 64;
      const bf16* vpt = vp + (t + 1) * 64;
      bf16* Kd = smem + (buf ^ 1) * 8192;
#pragma unroll
      for (int p = 0; p < 2; ++p) {
        GLOAD16(kpt + kgoff[p], Kd + ldsoff[p]);
        GLOAD16(vpt + vgoff[p], Kd + 4096 + ldsoff[p]);
      }
    }
    const bf16* Kc = smem + buf * 8192;
    const bf16* Vc = Kc + 4096;

    // S^T = K' * Q
    f32x4 s[4][2];
#pragma unroll
    for (int mk = 0; mk < 4; ++mk)
#pragma unroll
      for (int nq = 0; nq < 2; ++nq) s[mk][nq] = zero;
#pragma unroll
    for (int ks = 0; ks < 2; ++ks) {
      bf16x8 kb[4];
#pragma unroll
      for (int mk = 0; mk < 4; ++mk) {
        int row = mk * 16 + l15;
        int kc = ks * 4 + l4;
        kb[mk] = *(const bf16x8*)(Kc + row * 64 + ((kc ^ (row & 7)) << 3));
      }
      __builtin_amdgcn_s_setprio(1);
#pragma unroll
      for (int mk = 0; mk < 4; ++mk)
#pragma unroll
        for (int nq = 0; nq < 2; ++nq)
          s[mk][nq] = mfma16(kb[mk], qf[nq][ks], s[mk][nq]);
      __builtin_amdgcn_s_setprio(0);
    }

    // in-register online softmax; stats per q (= lane l15, per nq)
    float pmax[2], need = 0.f;
#pragma unroll
    for (int nq = 0; nq < 2; ++nq) {
      float a0 = fmaxf(fmaxf(s[0][nq][0], s[0][nq][1]),
                       fmaxf(s[0][nq][2], s[0][nq][3]));
      float a1 = fmaxf(fmaxf(s[1][nq][0], s[1][nq][1]),
                       fmaxf(s[1][nq][2], s[1][nq][3]));
      float a2 = fmaxf(fmaxf(s[2][nq][0], s[2][nq][1]),
                       fmaxf(s[2][nq][2], s[2][nq][3]));
      float a3 = fmaxf(fmaxf(s[3][nq][0], s[3][nq][1]),
                       fmaxf(s[3][nq][2], s[3][nq][3]));
      float v = fmaxf(fmaxf(a0, a1), fmaxf(a2, a3));
      v = fmaxf(v, __shfl_xor(v, 16));
      v = fmaxf(v, __shfl_xor(v, 32));
      pmax[nq] = v;
      need = fmaxf(need, v - m[nq]);
    }
    if (__any(need > 8.f)) {              // rare: real rescale (T13 defer-max)
#pragma unroll
      for (int nq = 0; nq < 2; ++nq) {
        float mnew = fmaxf(m[nq], pmax[nq]);
        float alpha = __expf(m[nq] - mnew);
#pragma unroll
        for (int di = 0; di < 4; ++di)
#pragma unroll
          for (int r = 0; r < 4; ++r) o[nq][di][r] *= alpha;
        l[nq] *= alpha;
        m[nq] = mnew;
      }
    }
    bf16x8 pf[2][2];                      // pf[nq][ks]
#pragma unroll
    for (int nq = 0; nq < 2; ++nq) {
      float rs = 0.f;
#pragma unroll
      for (int mk = 0; mk < 4; ++mk)
#pragma unroll
        for (int r = 0; r < 4; ++r) {
          float pv = __expf(s[mk][nq][r] - m[nq]);
          s[mk][nq][r] = pv;
          rs += pv;
        }
      rs += __shfl_xor(rs, 16);
      rs += __shfl_xor(rs, 32);
      l[nq] += rs;
#pragma unroll
      for (int ks = 0; ks < 2; ++ks) {
        bf16x8 t8;
#pragma unroll
        for (int r = 0; r < 4; ++r) {
          t8[r] = (bf16)s[2 * ks][nq][r];
          t8[4 + r] = (bf16)s[2 * ks + 1][nq][r];
        }
        pf[nq][ks] = t8;
      }
    }

    // O^T += V^T * P
#pragma unroll
    for (int ks = 0; ks < 2; ++ks) {
      bf16x8 vb[4];
#pragma unroll
      for (int di = 0; di < 4; ++di) {
        int row = di * 16 + l15;
        int kc = ks * 4 + l4;
        vb[di] = *(const bf16x8*)(Vc + row * 64 + ((kc ^ (row & 7)) << 3));
      }
      __builtin_amdgcn_s_setprio(1);
#pragma unroll
      for (int di = 0; di < 4; ++di)
#pragma unroll
        for (int nq = 0; nq < 2; ++nq)
          o[nq][di] = mfma16(vb[di], pf[nq][ks], o[nq][di]);
      __builtin_amdgcn_s_setprio(0);
    }
    __syncthreads();
  }

  // epilogue: O^T[d][q] -> ao[b][t=q][h*64+d]
  const int b = bh >> 3, h = bh & 7;
#pragma unroll
  for (int nq = 0; nq < 2; ++nq) {
    float inv = 1.f / l[nq];
    int trow = qw0 + nq * 16 + l15;
#pragma unroll
    for (int di = 0; di < 4; ++di) {
      bf16x4v pk;
#pragma unroll
      for (int r = 0; r < 4; ++r) pk[r] = (bf16)(o[nq][di][r] * inv);
      *(bf16x4v*)(ao + ((size_t)(b * T_N + trow)) * C_N + h * 64 + di * 16 +
                  l4 * 4) = pk;
    }
  }
}

// -------------------------------------------------------------- out projection
__global__ __launch_bounds__(256) void gemm_out(
    const bf16* __restrict__ wo, const bf16* __restrict__ ao,
    const float* __restrict__ bo, const float* __restrict__ x,
    float* __restrict__ out) {
  __shared__ bf16 lds[2 * 128 * 64];
  const int m0 = blockIdx.x * 128;
  const int n0 = blockIdx.y * 128;
  const int b = blockIdx.z;
  f32x4 acc[4][4];
  gemm128_core<512>(wo + (size_t)m0 * 512,
                    ao + (size_t)b * T_N * C_N + (size_t)n0 * 512,
                    lds, lds + 128 * 64, acc);
  const int tid = threadIdx.x, lane = tid & 63, wave = tid >> 6;
  const int wm = wave >> 1, wn = wave & 1;
  const int l15 = lane & 15, l4 = lane >> 4;
#pragma unroll
  for (int i = 0; i < 4; ++i) {
#pragma unroll
    for (int r = 0; r < 4; ++r) {
      int cr_ = m0 + wm * 64 + i * 16 + l4 * 4 + r;
      float bias = bo[cr_];
      const float* xrow = x + ((size_t)b * C_N + cr_) * T_N;
      float* orow = out + ((size_t)b * C_N + cr_) * T_N;
#pragma unroll
      for (int j = 0; j < 4; ++j) {
        int tc = n0 + wn * 64 + j * 16 + l15;
        orow[tc] = acc[i][j][r] + bias + xrow[tc];
      }
    }
  }
}

// ------------------------------------------------------------------- launcher
extern "C" void kernel_launch(void* const* d_in, const int* in_sizes, int n_in,
                              void* d_out, int out_size, void* d_ws,
                              size_t ws_size, hipStream_t stream) {
  const float* x = (const float*)d_in[0];
  const float* Wq = (const float*)d_in[1];
  const float* bq = (const float*)d_in[2];
  const float* Wk = (const float*)d_in[3];
  const float* bk = (const float*)d_in[4];
  const float* Wv = (const float*)d_in[5];
  const float* bv = (const float*)d_in[6];
  const float* Wo = (const float*)d_in[7];
  const float* bo = (const float*)d_in[8];
  const float* gamma = (const float*)d_in[9];
  const float* beta = (const float*)d_in[10];
  float* out = (float*)d_out;

  bf16* wq_b = (bf16*)d_ws;
  bf16* wk_b = wq_b + 262144;
  bf16* wv_b = wk_b + 262144;
  bf16* wo_b = wv_b + 262144;
  bf16* xn = wo_b + 262144;
  bf16* qb = xn + (size_t)8192 * 512;
  bf16* kb = qb + (size_t)4194304;
  bf16* vtb = kb + (size_t)4194304;
  bf16* aob = vtb + (size_t)4194304;

  cvt_w<<<dim3(256, 4), 256, 0, stream>>>(Wq, Wk, Wv, Wo, wq_b, wk_b, wv_b, wo_b);
  ln_tr<<<dim3(T_N / 32, B_N), 256, 0, stream>>>(x, gamma, beta, xn);
  gemm_qkv<<<dim3(64, 4, 3), 256, 0, stream>>>(xn, wq_b, wk_b, wv_b, bq, bk, bv,
                                               qb, kb, vtb);
  attn<<<dim3(T_N / 128, B_N * H_N), 256, 0, stream>>>(qb, kb, vtb, aob);
  gemm_out<<<dim3(4, 16, 4), 256, 0, stream>>>(wo_b, aob, bo, x, out);
}

// Round 5
// 117.206 us; speedup vs baseline: 1.6407x; 1.0672x over previous
//
#include <hip/hip_runtime.h>
#include <stdint.h>

typedef __bf16 bf16;
typedef __bf16 bf16x8 __attribute__((ext_vector_type(8)));
typedef __bf16 bf16x4v __attribute__((ext_vector_type(4)));
typedef float f32x4 __attribute__((ext_vector_type(4)));

constexpr int B_N = 4, C_N = 512, T_N = 2048, H_N = 8, D_N = 64;

__device__ __forceinline__ f32x4 mfma16(bf16x8 a, bf16x8 b, f32x4 c) {
  return __builtin_amdgcn_mfma_f32_16x16x32_bf16(a, b, c, 0, 0, 0);
}

__device__ __forceinline__ float exp2_fast(float x) {
  return __builtin_amdgcn_exp2f(x);   // v_exp_f32: 2^x
}

#define GLOAD16(gp, lp)                                                        \
  __builtin_amdgcn_global_load_lds(                                            \
      (__attribute__((address_space(1))) void*)(uintptr_t)(const void*)(gp),   \
      (__attribute__((address_space(3))) void*)(uintptr_t)(void*)(lp), 16, 0, 0)

// ---------------------------------------------------------------- cvt weights
__global__ __launch_bounds__(256) void cvt_w(
    const float* __restrict__ w0, const float* __restrict__ w1,
    const float* __restrict__ w2, const float* __restrict__ w3,
    bf16* __restrict__ o0, bf16* __restrict__ o1,
    bf16* __restrict__ o2, bf16* __restrict__ o3) {
  int which = blockIdx.y;
  const float* s = which == 0 ? w0 : which == 1 ? w1 : which == 2 ? w2 : w3;
  bf16* d = which == 0 ? o0 : which == 1 ? o1 : which == 2 ? o2 : o3;
  int i = blockIdx.x * 256 + threadIdx.x;
  float4 v = ((const float4*)s)[i];
  bf16x4v pk = {(bf16)v.x, (bf16)v.y, (bf16)v.z, (bf16)v.w};
  *(bf16x4v*)(d + (size_t)i * 4) = pk;
}

// -------------------------------------------------- LayerNorm + transpose
__global__ __launch_bounds__(256) void ln_tr(
    const float* __restrict__ x, const float* __restrict__ gamma,
    const float* __restrict__ beta, bf16* __restrict__ xn) {
  __shared__ bf16 tile[32 * 520];
  __shared__ float red[2][8][32];
  __shared__ float mu_s[32], rs_s[32];
  const int b = blockIdx.y;
  const int t0 = blockIdx.x * 32;
  const int tid = threadIdx.x;
  const int lt = tid & 31;
  const int cr = tid >> 5;
  const float* xp = x + ((size_t)b * C_N) * T_N + t0 + lt;
  float sum = 0.f, ss = 0.f;
  for (int c = cr; c < C_N; c += 8) {
    float v = xp[(size_t)c * T_N];
    tile[lt * 520 + c] = (bf16)v;
    sum += v;
    ss += v * v;
  }
  red[0][cr][lt] = sum;
  red[1][cr][lt] = ss;
  __syncthreads();
  if (tid < 32) {
    float s = 0.f, q = 0.f;
    for (int j = 0; j < 8; ++j) { s += red[0][j][tid]; q += red[1][j][tid]; }
    float mu = s * (1.f / 512.f);
    float var = q * (1.f / 512.f) - mu * mu;
    mu_s[tid] = mu;
    rs_s[tid] = rsqrtf(var + 1e-5f);
  }
  __syncthreads();
#pragma unroll
  for (int p = 0; p < 8; ++p) {
    int ch = p * 256 + tid;
    int t = ch >> 6;
    int c0 = (ch & 63) * 8;
    float mu = mu_s[t], rs = rs_s[t];
    bf16x8 in = *(const bf16x8*)(tile + t * 520 + c0);
    bf16x8 ov;
#pragma unroll
    for (int e = 0; e < 8; ++e) {
      float g = gamma[c0 + e], bb = beta[c0 + e];
      ov[e] = (bf16)(((float)in[e] - mu) * rs * g + bb);
    }
    *(bf16x8*)(xn + ((size_t)(b * T_N + t0 + t)) * C_N + c0) = ov;
  }
}

// ------------------------------------------------ shared 128x128x(K) GEMM core
template <int KDIM>
__device__ __forceinline__ void gemm128_core(const bf16* __restrict__ Ag,
                                             const bf16* __restrict__ Bg,
                                             bf16* As, bf16* Bs,
                                             f32x4 acc[4][4]) {
  const int tid = threadIdx.x;
  const int lane = tid & 63;
  const int wave = tid >> 6;
  const int wm = wave >> 1, wn = wave & 1;
  const int l15 = lane & 15, l4 = lane >> 4;
  f32x4 zero = {0.f, 0.f, 0.f, 0.f};
#pragma unroll
  for (int i = 0; i < 4; ++i)
#pragma unroll
    for (int j = 0; j < 4; ++j) acc[i][j] = zero;

  for (int kt = 0; kt < KDIM / 64; ++kt) {
    const bf16* a0 = Ag + kt * 64;
    const bf16* b0 = Bg + kt * 64;
#pragma unroll
    for (int p = 0; p < 4; ++p) {
      int chunk = p * 256 + tid;
      int row = chunk >> 3, c = chunk & 7;
      int sc = c ^ (row & 7);
      GLOAD16(a0 + (size_t)row * KDIM + sc * 8, As + chunk * 8);
      GLOAD16(b0 + (size_t)row * KDIM + sc * 8, Bs + chunk * 8);
    }
    __syncthreads();
#pragma unroll
    for (int ks = 0; ks < 2; ++ks) {
      bf16x8 af[4], bfr[4];
#pragma unroll
      for (int i = 0; i < 4; ++i) {
        int row = wm * 64 + i * 16 + l15;
        int kc = ks * 4 + l4;
        af[i] = *(const bf16x8*)(As + row * 64 + ((kc ^ (row & 7)) << 3));
      }
#pragma unroll
      for (int j = 0; j < 4; ++j) {
        int row = wn * 64 + j * 16 + l15;
        int kc = ks * 4 + l4;
        bfr[j] = *(const bf16x8*)(Bs + row * 64 + ((kc ^ (row & 7)) << 3));
      }
#pragma unroll
      for (int i = 0; i < 4; ++i)
#pragma unroll
        for (int j = 0; j < 4; ++j) acc[i][j] = mfma16(af[i], bfr[j], acc[i][j]);
    }
    __syncthreads();
  }
}

// ---------------------------------------------------------------- QKV GEMM
__global__ __launch_bounds__(256) void gemm_qkv(
    const bf16* __restrict__ xn, const bf16* __restrict__ wq,
    const bf16* __restrict__ wk, const bf16* __restrict__ wv,
    const float* __restrict__ bq, const float* __restrict__ bk,
    const float* __restrict__ bv, bf16* __restrict__ q, bf16* __restrict__ k,
    bf16* __restrict__ vt) {
  __shared__ bf16 lds[128 * 136];
  bf16* As = lds;
  bf16* Bs = lds + 128 * 64;
  const int z = blockIdx.z;
  const bf16* W = z == 0 ? wq : z == 1 ? wk : wv;
  const float* bias = z == 0 ? bq : z == 1 ? bk : bv;
  const int m0 = blockIdx.x * 128;
  const int n0 = blockIdx.y * 128;
  f32x4 acc[4][4];
  gemm128_core<512>(xn + (size_t)m0 * 512, W + (size_t)n0 * 512, As, Bs, acc);

  const int tid = threadIdx.x, lane = tid & 63, wave = tid >> 6;
  const int wm = wave >> 1, wn = wave & 1;
  const int l15 = lane & 15, l4 = lane >> 4;
  const int b = m0 >> 11;
  const int t0 = m0 & (T_N - 1);

  if (z < 2) {
    bf16* outp = z == 0 ? q : k;
#pragma unroll
    for (int i = 0; i < 4; ++i) {
      int t = t0 + wm * 64 + i * 16 + l4 * 4;
#pragma unroll
      for (int j = 0; j < 4; ++j) {
        int n = n0 + wn * 64 + j * 16 + l15;
        int h = n >> 6, d = n & 63;
        bf16* dst = outp + (((size_t)(b * H_N + h) * T_N) + t) * D_N + d;
        float bv_ = bias[n];
#pragma unroll
        for (int r = 0; r < 4; ++r) dst[(size_t)r * D_N] = (bf16)(acc[i][j][r] + bv_);
      }
    }
  } else {
#pragma unroll
    for (int i = 0; i < 4; ++i) {
      int ml = wm * 64 + i * 16 + l4 * 4;
#pragma unroll
      for (int j = 0; j < 4; ++j) {
        int nl = wn * 64 + j * 16 + l15;
        float bv_ = bias[n0 + nl];
#pragma unroll
        for (int r = 0; r < 4; ++r) lds[nl * 136 + ml + r] = (bf16)(acc[i][j][r] + bv_);
      }
    }
    __syncthreads();
#pragma unroll
    for (int p = 0; p < 8; ++p) {
      int ch = p * 256 + tid;
      int row = ch >> 4;
      int cm = (ch & 15) * 8;
      int n = n0 + row;
      int h = n >> 6, d = n & 63;
      bf16x8 v = *(const bf16x8*)(lds + row * 136 + cm);
      *(bf16x8*)(vt + (((size_t)(b * H_N + h) * D_N + d) * T_N) + t0 + cm) = v;
    }
  }
}

// ---------------------------------------------------------------- attention
// Swapped-operand flash attention, 8 waves x 32 q-rows (Q-tile 256).
// S^T = mfma(K',Q), O^T = mfma(V^T,P); K rows bit-permuted in LDS so P stays
// in registers. Softmax in exp2 domain. REG-STAGED double buffer (plain
// global loads -> VGPR -> ds_write) so no async-load/barrier ordering hazard.
__global__ __launch_bounds__(512, 2) void attn(const bf16* __restrict__ q,
                                               const bf16* __restrict__ kk,
                                               const bf16* __restrict__ vt,
                                               bf16* __restrict__ ao) {
  __shared__ __align__(16) bf16 smem[16384];  // 2 bufs x (K 4096 + V 4096)
  const int bh = blockIdx.y;
  const int q0 = blockIdx.x * 256;
  const int tid = threadIdx.x, lane = tid & 63, wave = tid >> 6;  // 8 waves
  const int l15 = lane & 15, l4 = lane >> 4;
  const bf16* qp = q + (size_t)bh * T_N * D_N;
  const bf16* kp = kk + (size_t)bh * T_N * D_N;
  const bf16* vp = vt + (size_t)bh * D_N * T_N;
  const int qw0 = q0 + wave * 32;

  // staging source offsets: thread stages one 16B K chunk + one 16B V chunk
  // K source row bit-permuted: rho=[b5 b4 b3 b2 b1 b0] -> kv=b5*32+(b3b2)*8+b4*4+(b1b0)
  const int srow = tid >> 3, scc = tid & 7;
  const int ssc = scc ^ (srow & 7);
  const int kvp = (srow & 0x23) | ((srow & 0x0C) << 1) | ((srow & 0x10) >> 2);
  const int kgoff = kvp * 64 + ssc * 8;
  const int vgoff = srow * T_N + ssc * 8;

  // Q fragments (B-operand), pre-scaled by 0.125*log2(e)
  bf16x8 qf[2][2];
#pragma unroll
  for (int nq = 0; nq < 2; ++nq)
#pragma unroll
    for (int ks = 0; ks < 2; ++ks) {
      bf16x8 v = *(const bf16x8*)(qp + (size_t)(qw0 + nq * 16 + l15) * D_N +
                                  ks * 32 + l4 * 8);
#pragma unroll
      for (int e = 0; e < 8; ++e) v[e] = (bf16)((float)v[e] * 0.180336880f);
      qf[nq][ks] = v;
    }

  f32x4 zero = {0.f, 0.f, 0.f, 0.f};
  f32x4 o[2][4];                    // o[nq][di]: O^T[d=di*16+l4*4+r][q=l15]
  float m[2] = {-1e30f, -1e30f}, l[2] = {0.f, 0.f};
#pragma unroll
  for (int nq = 0; nq < 2; ++nq)
#pragma unroll
    for (int di = 0; di < 4; ++di) o[nq][di] = zero;

  constexpr int NT = T_N / 64;      // 32
  // prologue: tile0 -> regs -> buf0; issue tile1 -> regs
  bf16x8 kreg = *(const bf16x8*)(kp + kgoff);
  bf16x8 vreg = *(const bf16x8*)(vp + vgoff);
  *(bf16x8*)(smem + tid * 8) = kreg;
  *(bf16x8*)(smem + 4096 + tid * 8) = vreg;
  kreg = *(const bf16x8*)(kp + 64 * 64 + kgoff);
  vreg = *(const bf16x8*)(vp + 64 + vgoff);
  __syncthreads();

  for (int t = 0; t < NT; ++t) {
    const int buf = t & 1;
    const bf16* Kc = smem + buf * 8192;
    const bf16* Vc = Kc + 4096;

    // S^T = K' * Q
    f32x4 s[4][2];
#pragma unroll
    for (int mk = 0; mk < 4; ++mk)
#pragma unroll
      for (int nq = 0; nq < 2; ++nq) s[mk][nq] = zero;
#pragma unroll
    for (int ks = 0; ks < 2; ++ks) {
      bf16x8 kb[4];
#pragma unroll
      for (int mk = 0; mk < 4; ++mk) {
        int row = mk * 16 + l15;
        int kc = ks * 4 + l4;
        kb[mk] = *(const bf16x8*)(Kc + row * 64 + ((kc ^ (row & 7)) << 3));
      }
      __builtin_amdgcn_s_setprio(1);
#pragma unroll
      for (int mk = 0; mk < 4; ++mk)
#pragma unroll
        for (int nq = 0; nq < 2; ++nq)
          s[mk][nq] = mfma16(kb[mk], qf[nq][ks], s[mk][nq]);
      __builtin_amdgcn_s_setprio(0);
    }

    // stage tile t+1 (already in regs) into the other buffer; issue t+2 loads
    if (t + 1 < NT) {
      bf16* Kd = smem + (buf ^ 1) * 8192;
      *(bf16x8*)(Kd + tid * 8) = kreg;
      *(bf16x8*)(Kd + 4096 + tid * 8) = vreg;
      if (t + 2 < NT) {
        kreg = *(const bf16x8*)(kp + (t + 2) * 64 * 64 + kgoff);
        vreg = *(const bf16x8*)(vp + (t + 2) * 64 + vgoff);
      }
    }

    // in-register online softmax (exp2 domain); stats per q (= lane l15)
    float pmax[2], need = 0.f;
#pragma unroll
    for (int nq = 0; nq < 2; ++nq) {
      float a0 = fmaxf(fmaxf(s[0][nq][0], s[0][nq][1]),
                       fmaxf(s[0][nq][2], s[0][nq][3]));
      float a1 = fmaxf(fmaxf(s[1][nq][0], s[1][nq][1]),
                       fmaxf(s[1][nq][2], s[1][nq][3]));
      float a2 = fmaxf(fmaxf(s[2][nq][0], s[2][nq][1]),
                       fmaxf(s[2][nq][2], s[2][nq][3]));
      float a3 = fmaxf(fmaxf(s[3][nq][0], s[3][nq][1]),
                       fmaxf(s[3][nq][2], s[3][nq][3]));
      float v = fmaxf(fmaxf(a0, a1), fmaxf(a2, a3));
      v = fmaxf(v, __shfl_xor(v, 16));
      v = fmaxf(v, __shfl_xor(v, 32));
      pmax[nq] = v;
      need = fmaxf(need, v - m[nq]);
    }
    if (__any(need > 8.f)) {        // rare (defer-max)
#pragma unroll
      for (int nq = 0; nq < 2; ++nq) {
        float mnew = fmaxf(m[nq], pmax[nq]);
        float alpha = exp2_fast(m[nq] - mnew);
#pragma unroll
        for (int di = 0; di < 4; ++di)
#pragma unroll
          for (int r = 0; r < 4; ++r) o[nq][di][r] *= alpha;
        l[nq] *= alpha;
        m[nq] = mnew;
      }
    }
    bf16x8 pf[2][2];                // pf[nq][ks]
#pragma unroll
    for (int nq = 0; nq < 2; ++nq) {
      float rs = 0.f;
#pragma unroll
      for (int mk = 0; mk < 4; ++mk)
#pragma unroll
        for (int r = 0; r < 4; ++r) {
          float pv = exp2_fast(s[mk][nq][r] - m[nq]);
          s[mk][nq][r] = pv;
          rs += pv;
        }
      rs += __shfl_xor(rs, 16);
      rs += __shfl_xor(rs, 32);
      l[nq] += rs;
#pragma unroll
      for (int ks = 0; ks < 2; ++ks) {
        bf16x8 t8;
#pragma unroll
        for (int r = 0; r < 4; ++r) {
          t8[r] = (bf16)s[2 * ks][nq][r];
          t8[4 + r] = (bf16)s[2 * ks + 1][nq][r];
        }
        pf[nq][ks] = t8;
      }
    }

    // O^T += V^T * P
#pragma unroll
    for (int ks = 0; ks < 2; ++ks) {
      bf16x8 vb[4];
#pragma unroll
      for (int di = 0; di < 4; ++di) {
        int row = di * 16 + l15;
        int kc = ks * 4 + l4;
        vb[di] = *(const bf16x8*)(Vc + row * 64 + ((kc ^ (row & 7)) << 3));
      }
      __builtin_amdgcn_s_setprio(1);
#pragma unroll
      for (int di = 0; di < 4; ++di)
#pragma unroll
        for (int nq = 0; nq < 2; ++nq)
          o[nq][di] = mfma16(vb[di], pf[nq][ks], o[nq][di]);
      __builtin_amdgcn_s_setprio(0);
    }
    __syncthreads();
  }

  // epilogue: O^T[d][q] -> ao[b][t=q][h*64+d]
  const int b = bh >> 3, h = bh & 7;
#pragma unroll
  for (int nq = 0; nq < 2; ++nq) {
    float inv = 1.f / l[nq];
    int trow = qw0 + nq * 16 + l15;
#pragma unroll
    for (int di = 0; di < 4; ++di) {
      bf16x4v pk;
#pragma unroll
      for (int r = 0; r < 4; ++r) pk[r] = (bf16)(o[nq][di][r] * inv);
      *(bf16x4v*)(ao + ((size_t)(b * T_N + trow)) * C_N + h * 64 + di * 16 +
                  l4 * 4) = pk;
    }
  }
}

// -------------------------------------------------------------- out projection
__global__ __launch_bounds__(256) void gemm_out(
    const bf16* __restrict__ wo, const bf16* __restrict__ ao,
    const float* __restrict__ bo, const float* __restrict__ x,
    float* __restrict__ out) {
  __shared__ bf16 lds[2 * 128 * 64];
  const int m0 = blockIdx.x * 128;
  const int n0 = blockIdx.y * 128;
  const int b = blockIdx.z;
  f32x4 acc[4][4];
  gemm128_core<512>(wo + (size_t)m0 * 512,
                    ao + (size_t)b * T_N * C_N + (size_t)n0 * 512,
                    lds, lds + 128 * 64, acc);
  const int tid = threadIdx.x, lane = tid & 63, wave = tid >> 6;
  const int wm = wave >> 1, wn = wave & 1;
  const int l15 = lane & 15, l4 = lane >> 4;
#pragma unroll
  for (int i = 0; i < 4; ++i) {
#pragma unroll
    for (int r = 0; r < 4; ++r) {
      int cr_ = m0 + wm * 64 + i * 16 + l4 * 4 + r;
      float bias = bo[cr_];
      const float* xrow = x + ((size_t)b * C_N + cr_) * T_N;
      float* orow = out + ((size_t)b * C_N + cr_) * T_N;
#pragma unroll
      for (int j = 0; j < 4; ++j) {
        int tc = n0 + wn * 64 + j * 16 + l15;
        orow[tc] = acc[i][j][r] + bias + xrow[tc];
      }
    }
  }
}

// ------------------------------------------------------------------- launcher
extern "C" void kernel_launch(void* const* d_in, const int* in_sizes, int n_in,
                              void* d_out, int out_size, void* d_ws,
                              size_t ws_size, hipStream_t stream) {
  const float* x = (const float*)d_in[0];
  const float* Wq = (const float*)d_in[1];
  const float* bq = (const float*)d_in[2];
  const float* Wk = (const float*)d_in[3];
  const float* bk = (const float*)d_in[4];
  const float* Wv = (const float*)d_in[5];
  const float* bv = (const float*)d_in[6];
  const float* Wo = (const float*)d_in[7];
  const float* bo = (const float*)d_in[8];
  const float* gamma = (const float*)d_in[9];
  const float* beta = (const float*)d_in[10];
  float* out = (float*)d_out;

  bf16* wq_b = (bf16*)d_ws;
  bf16* wk_b = wq_b + 262144;
  bf16* wv_b = wk_b + 262144;
  bf16* wo_b = wv_b + 262144;
  bf16* xn = wo_b + 262144;
  bf16* qb = xn + (size_t)8192 * 512;
  bf16* kb = qb + (size_t)4194304;
  bf16* vtb = kb + (size_t)4194304;
  bf16* aob = vtb + (size_t)4194304;

  cvt_w<<<dim3(256, 4), 256, 0, stream>>>(Wq, Wk, Wv, Wo, wq_b, wk_b, wv_b, wo_b);
  ln_tr<<<dim3(T_N / 32, B_N), 256, 0, stream>>>(x, gamma, beta, xn);
  gemm_qkv<<<dim3(64, 4, 3), 256, 0, stream>>>(xn, wq_b, wk_b, wv_b, bq, bk, bv,
                                               qb, kb, vtb);
  attn<<<dim3(T_N / 256, B_N * H_N), 512, 0, stream>>>(qb, kb, vtb, aob);
  gemm_out<<<dim3(4, 16, 4), 256, 0, stream>>>(wo_b, aob, bo, x, out);
}